// Round 2
// baseline (1599.938 us; speedup 1.0000x reference)
//
#include <hip/hip_runtime.h>
#include <stdint.h>

#define F_IN 128
#define HDIM 16
#define CDIM 4

// ---------------------------------------------------------------------------
// Detect whether edge_index buffer is int64 (odd 32-bit words all zero) or
// int32 (odd words are random edge ids). Writes flag: 1 = int64, 0 = int32.
// ---------------------------------------------------------------------------
__global__ void k_detect(const int* __restrict__ w, int* __restrict__ flag) {
    __shared__ int s_any;
    if (threadIdx.x == 0) s_any = 0;
    __syncthreads();
    int nz = 0;
    for (int k = threadIdx.x; k < 1024; k += blockDim.x) nz |= w[2 * k + 1];
    if (nz) atomicOr(&s_any, 1);
    __syncthreads();
    if (threadIdx.x == 0) *flag = (s_any == 0) ? 1 : 0;
}

// deg starts at 1.0 (self-loop); accumulators zeroed (ws is poisoned 0xAA).
__global__ void k_init(float* __restrict__ deg, float* __restrict__ o1,
                       float* __restrict__ o2, int n) {
    int i = blockIdx.x * blockDim.x + threadIdx.x;
    if (i < n) deg[i] = 1.0f;
    if (i < n * HDIM) o1[i] = 0.0f;
    if (i < n * CDIM) o2[i] = 0.0f;
}

__global__ void k_deg(const void* __restrict__ ei, const int* __restrict__ flag,
                      float* __restrict__ deg, int E) {
    int e = blockIdx.x * blockDim.x + threadIdx.x;
    if (e >= E) return;
    int d;
    if (*flag) d = (int)((const long long*)ei)[E + e];
    else       d = ((const int*)ei)[E + e];
    atomicAdd(&deg[d], 1.0f);
}

__global__ void k_rsqrt(float* __restrict__ deg, int n) {
    int i = blockIdx.x * blockDim.x + threadIdx.x;
    if (i < n) deg[i] = rsqrtf(deg[i]);
}

// h1 = x @ W1   [n,128]@[128,16]  — LDS-tiled, 16 rows per 256-thread block.
__global__ __launch_bounds__(256) void k_gemm1(const float* __restrict__ x,
                                               const float* __restrict__ W1,
                                               float* __restrict__ h1, int n) {
    __shared__ float sW[F_IN * HDIM];
    __shared__ float sX[16][F_IN + 4];  // +4 pad: r*132 % 32 varies -> no conflict
    for (int i = threadIdx.x; i < F_IN * HDIM; i += 256) sW[i] = W1[i];
    int row0 = blockIdx.x * 16;
    const float4* x4 = (const float4*)(x + (size_t)row0 * F_IN);
    for (int i = threadIdx.x; i < 512; i += 256) {
        int r = i >> 5, c4 = i & 31;
        if (row0 + r < n) *(float4*)&sX[r][c4 * 4] = x4[i];
    }
    __syncthreads();
    int c = threadIdx.x & 15, r = threadIdx.x >> 4;
    float acc = 0.f;
#pragma unroll
    for (int k = 0; k < F_IN; ++k) acc += sX[r][k] * sW[k * HDIM + c];
    if (row0 + r < n) h1[(size_t)(row0 + r) * HDIM + c] = acc;
}

// Layer-1 aggregation: 4 threads per edge, each a float4 slice of the 16-wide
// feature row. Edges [0,E) from the buffer; [E, E+n) are implicit self-loops.
__global__ void k_agg1(const void* __restrict__ ei, const int* __restrict__ flag,
                       const float* __restrict__ dinv, const float* __restrict__ h1,
                       float* __restrict__ o1, int E, int n) {
    int t = blockIdx.x * blockDim.x + threadIdx.x;
    int e = t >> 2, p = t & 3;
    if (e >= E + n) return;
    int s, d;
    if (e < E) {
        if (*flag) {
            const long long* q = (const long long*)ei;
            s = (int)q[e]; d = (int)q[E + e];
        } else {
            const int* q = (const int*)ei;
            s = q[e]; d = q[E + e];
        }
    } else {
        s = d = e - E;
    }
    float w = dinv[s] * dinv[d];
    float4 v = ((const float4*)h1)[s * 4 + p];
    float* o = o1 + (size_t)d * HDIM + p * 4;
    atomicAdd(o + 0, v.x * w);
    atomicAdd(o + 1, v.y * w);
    atomicAdd(o + 2, v.z * w);
    atomicAdd(o + 3, v.w * w);
}

// Per-node: bias + relu + (16x4) GEMM in registers.
__global__ void k_node2(const float* __restrict__ o1, const float* __restrict__ b1,
                        const float* __restrict__ W2, float* __restrict__ h2, int n) {
    int i = blockIdx.x * blockDim.x + threadIdx.x;
    if (i >= n) return;
    float t[HDIM];
    const float4* r4 = (const float4*)(o1 + (size_t)i * HDIM);
#pragma unroll
    for (int j = 0; j < 4; ++j) {
        float4 v = r4[j];
        t[4 * j + 0] = fmaxf(v.x + b1[4 * j + 0], 0.f);
        t[4 * j + 1] = fmaxf(v.y + b1[4 * j + 1], 0.f);
        t[4 * j + 2] = fmaxf(v.z + b1[4 * j + 2], 0.f);
        t[4 * j + 3] = fmaxf(v.w + b1[4 * j + 3], 0.f);
    }
    float a0 = 0.f, a1 = 0.f, a2 = 0.f, a3 = 0.f;
#pragma unroll
    for (int j = 0; j < HDIM; ++j) {
        float tv = t[j];
        a0 += tv * W2[j * 4 + 0];
        a1 += tv * W2[j * 4 + 1];
        a2 += tv * W2[j * 4 + 2];
        a3 += tv * W2[j * 4 + 3];
    }
    ((float4*)h2)[i] = make_float4(a0, a1, a2, a3);
}

// Layer-2 aggregation: 1 thread per edge (+ self-loops), 4 atomics each.
__global__ void k_agg2(const void* __restrict__ ei, const int* __restrict__ flag,
                       const float* __restrict__ dinv, const float* __restrict__ h2,
                       float* __restrict__ o2, int E, int n) {
    int e = blockIdx.x * blockDim.x + threadIdx.x;
    if (e >= E + n) return;
    int s, d;
    if (e < E) {
        if (*flag) {
            const long long* q = (const long long*)ei;
            s = (int)q[e]; d = (int)q[E + e];
        } else {
            const int* q = (const int*)ei;
            s = q[e]; d = q[E + e];
        }
    } else {
        s = d = e - E;
    }
    float w = dinv[s] * dinv[d];
    float4 v = ((const float4*)h2)[s];
    float* o = o2 + (size_t)d * CDIM;
    atomicAdd(o + 0, v.x * w);
    atomicAdd(o + 1, v.y * w);
    atomicAdd(o + 2, v.z * w);
    atomicAdd(o + 3, v.w * w);
}

__global__ void k_lsm(const float* __restrict__ o2, const float* __restrict__ b2,
                      float* __restrict__ out, int n) {
    int i = blockIdx.x * blockDim.x + threadIdx.x;
    if (i >= n) return;
    float4 v = ((const float4*)o2)[i];
    float z0 = v.x + b2[0], z1 = v.y + b2[1], z2 = v.z + b2[2], z3 = v.w + b2[3];
    float m = fmaxf(fmaxf(z0, z1), fmaxf(z2, z3));
    float s = expf(z0 - m) + expf(z1 - m) + expf(z2 - m) + expf(z3 - m);
    float l = m + logf(s);
    ((float4*)out)[i] = make_float4(z0 - l, z1 - l, z2 - l, z3 - l);
}

extern "C" void kernel_launch(void* const* d_in, const int* in_sizes, int n_in,
                              void* d_out, int out_size, void* d_ws, size_t ws_size,
                              hipStream_t stream) {
    const float* x  = (const float*)d_in[0];
    const void*  ei = d_in[1];
    const float* W1 = (const float*)d_in[2];
    const float* b1 = (const float*)d_in[3];
    const float* W2 = (const float*)d_in[4];
    const float* b2 = (const float*)d_in[5];
    float* out = (float*)d_out;

    int n = in_sizes[0] / F_IN;   // 100000
    int E = in_sizes[1] / 2;      // 3200000

    char* ws    = (char*)d_ws;
    int*  flag  = (int*)ws;
    float* dinv = (float*)(ws + 256);            // n floats (deg then dinv)
    float* h1   = dinv + n;                      // n*16
    float* o1   = h1 + (size_t)n * HDIM;         // n*16
    float* h2   = o1 + (size_t)n * HDIM;         // n*4
    float* o2   = h2 + (size_t)n * CDIM;         // n*4

    hipLaunchKernelGGL(k_detect, dim3(1), dim3(256), 0, stream, (const int*)ei, flag);
    hipLaunchKernelGGL(k_init, dim3((n * HDIM + 255) / 256), dim3(256), 0, stream,
                       dinv, o1, o2, n);
    hipLaunchKernelGGL(k_deg, dim3((E + 255) / 256), dim3(256), 0, stream,
                       ei, flag, dinv, E);
    hipLaunchKernelGGL(k_rsqrt, dim3((n + 255) / 256), dim3(256), 0, stream, dinv, n);
    hipLaunchKernelGGL(k_gemm1, dim3((n + 15) / 16), dim3(256), 0, stream,
                       x, W1, h1, n);
    int T1 = (E + n) * 4;
    hipLaunchKernelGGL(k_agg1, dim3((T1 + 255) / 256), dim3(256), 0, stream,
                       ei, flag, dinv, h1, o1, E, n);
    hipLaunchKernelGGL(k_node2, dim3((n + 255) / 256), dim3(256), 0, stream,
                       o1, b1, W2, h2, n);
    hipLaunchKernelGGL(k_agg2, dim3((E + n + 255) / 256), dim3(256), 0, stream,
                       ei, flag, dinv, h2, o2, E, n);
    hipLaunchKernelGGL(k_lsm, dim3((n + 255) / 256), dim3(256), 0, stream,
                       o2, b2, out, n);
}

// Round 7
// 615.975 us; speedup vs baseline: 2.5974x; 2.5974x over previous
//
#include <hip/hip_runtime.h>
#include <stdint.h>

#define F_IN 128
#define HDIM 16
#define CDIM 4

// ---------------------------------------------------------------------------
// Detect int64 vs int32 edge_index: odd 32-bit words of int64 values <2^31
// are all zero; for int32 data they're random node ids.
// ---------------------------------------------------------------------------
__global__ void k_detect(const int* __restrict__ w, int* __restrict__ flag) {
    __shared__ int s_any;
    if (threadIdx.x == 0) s_any = 0;
    __syncthreads();
    int nz = 0;
    for (int k = threadIdx.x; k < 1024; k += blockDim.x) nz |= w[2 * k + 1];
    if (nz) atomicOr(&s_any, 1);
    __syncthreads();
    if (threadIdx.x == 0) *flag = (s_any == 0) ? 1 : 0;
}

__global__ void k_zero_deg(int* __restrict__ deg_i, int n) {
    int i = blockIdx.x * blockDim.x + threadIdx.x;
    if (i < n) deg_i[i] = 0;
}

// In-degree histogram over dst (int atomics into L2-resident 400 KB).
__global__ __launch_bounds__(256) void k_hist(const void* __restrict__ ei,
                                              const int* __restrict__ flag,
                                              int* __restrict__ deg_i, int E) {
    int e = blockIdx.x * blockDim.x + threadIdx.x;
    if (e >= E) return;
    int d;
    if (*flag) d = (int)((const long long*)ei)[E + e];
    else       d = ((const int*)ei)[E + e];
    atomicAdd(&deg_i[d], 1);
}

// ---- 3-phase exclusive scan of deg_i -> row_ptr (1024 elems / block) ------
__global__ __launch_bounds__(256) void k_scan1(const int* __restrict__ deg_i,
                                               int* __restrict__ row_ptr,
                                               int* __restrict__ part, int n) {
    __shared__ int sd[256];
    int base = blockIdx.x * 1024, t = threadIdx.x;
    int v[4], ssum = 0;
#pragma unroll
    for (int k = 0; k < 4; ++k) {
        int i = base + t * 4 + k;
        v[k] = (i < n) ? deg_i[i] : 0;
        ssum += v[k];
    }
    sd[t] = ssum;
    __syncthreads();
    for (int off = 1; off < 256; off <<= 1) {
        int x = (t >= off) ? sd[t - off] : 0;
        __syncthreads();
        sd[t] += x;
        __syncthreads();
    }
    if (t == 255) part[blockIdx.x] = sd[255];
    int run = sd[t] - ssum;
#pragma unroll
    for (int k = 0; k < 4; ++k) {
        int i = base + t * 4 + k;
        if (i < n) row_ptr[i] = run;
        run += v[k];
    }
}

__global__ void k_scan2(int* __restrict__ part, int nb) {
    __shared__ int sd[128];
    int t = threadIdx.x;
    int own = (t < nb) ? part[t] : 0;
    sd[t] = own;
    __syncthreads();
    for (int off = 1; off < 128; off <<= 1) {
        int x = (t >= off) ? sd[t - off] : 0;
        __syncthreads();
        sd[t] += x;
        __syncthreads();
    }
    if (t < nb) part[t] = sd[t] - own;  // exclusive
}

__global__ void k_scan3(int* __restrict__ row_ptr, int* __restrict__ cursor,
                        const int* __restrict__ part, int n, int E) {
    int i = blockIdx.x * blockDim.x + threadIdx.x;
    if (i < n) {
        int r = row_ptr[i] + part[i >> 10];
        row_ptr[i] = r;
        cursor[i] = r;
    }
    if (i == 0) row_ptr[n] = E;
}

// dinv = rsqrt(in_degree + 1 self-loop)
__global__ void k_rsqrt(const int* __restrict__ deg_i, float* __restrict__ dinv,
                        int n) {
    int i = blockIdx.x * blockDim.x + threadIdx.x;
    if (i < n) dinv[i] = rsqrtf((float)(deg_i[i] + 1));
}

// Counting-sort scatter: csr_src[cursor[d]++] = s
__global__ __launch_bounds__(256) void k_scatter(const void* __restrict__ ei,
                                                 const int* __restrict__ flag,
                                                 int* __restrict__ cursor,
                                                 int* __restrict__ csr_src, int E) {
    int e = blockIdx.x * blockDim.x + threadIdx.x;
    if (e >= E) return;
    int s, d;
    if (*flag) {
        const long long* q = (const long long*)ei;
        s = (int)q[e]; d = (int)q[E + e];
    } else {
        const int* q = (const int*)ei;
        s = q[e]; d = q[E + e];
    }
    int pos = atomicAdd(&cursor[d], 1);
    csr_src[pos] = s;
}

// h1s = (x @ W1) * dinv[row]  — LDS-tiled, 16 rows / 256-thread block.
__global__ __launch_bounds__(256) void k_gemm1(const float* __restrict__ x,
                                               const float* __restrict__ W1,
                                               const float* __restrict__ dinv,
                                               float* __restrict__ h1s, int n) {
    __shared__ float sW[F_IN * HDIM];
    __shared__ float sX[16][F_IN + 4];
    for (int i = threadIdx.x; i < F_IN * HDIM; i += 256) sW[i] = W1[i];
    int row0 = blockIdx.x * 16;
    const float4* x4 = (const float4*)(x + (size_t)row0 * F_IN);
    for (int i = threadIdx.x; i < 512; i += 256) {
        int r = i >> 5, c4 = i & 31;
        if (row0 + r < n) *(float4*)&sX[r][c4 * 4] = x4[i];
    }
    __syncthreads();
    int c = threadIdx.x & 15, r = threadIdx.x >> 4;
    float acc = 0.f;
#pragma unroll
    for (int k = 0; k < F_IN; ++k) acc += sX[r][k] * sW[k * HDIM + c];
    int row = row0 + r;
    if (row < n) h1s[(size_t)row * HDIM + c] = acc * dinv[row];
}

// Layer-1 CSR aggregation fused with bias+relu+W2+src-scale.
// One wave per node: lane = f (0..15) + 16*slot (0..3).
__global__ __launch_bounds__(256) void k_agg1f(const int* __restrict__ row_ptr,
                                               const int* __restrict__ csr_src,
                                               const float* __restrict__ h1s,
                                               const float* __restrict__ dinv,
                                               const float* __restrict__ b1,
                                               const float* __restrict__ W2,
                                               float* __restrict__ h2s, int n) {
    int node = blockIdx.x * 4 + (threadIdx.x >> 6);
    if (node >= n) return;
    int lane = threadIdx.x & 63;
    int f = lane & 15, slot = lane >> 4;
    int start = row_ptr[node], end = row_ptr[node + 1];
    float acc = 0.f;
    for (int j = start + slot; j < end; j += 4)
        acc += h1s[(size_t)csr_src[j] * HDIM + f];
    acc += __shfl_xor(acc, 16, 64);
    acc += __shfl_xor(acc, 32, 64);
    float di = dinv[node];
    float t = fmaxf(di * (acc + h1s[(size_t)node * HDIM + f]) + b1[f], 0.f);
    float4 w2 = ((const float4*)W2)[f];
    float a0 = t * w2.x, a1 = t * w2.y, a2 = t * w2.z, a3 = t * w2.w;
#pragma unroll
    for (int m = 1; m < 16; m <<= 1) {
        a0 += __shfl_xor(a0, m, 64);
        a1 += __shfl_xor(a1, m, 64);
        a2 += __shfl_xor(a2, m, 64);
        a3 += __shfl_xor(a3, m, 64);
    }
    if (lane == 0)
        ((float4*)h2s)[node] = make_float4(a0 * di, a1 * di, a2 * di, a3 * di);
}

// Layer-2 CSR aggregation fused with bias + log_softmax.
// One wave per node: lane = c (0..3) + 4*slot (0..15).
__global__ __launch_bounds__(256) void k_agg2f(const int* __restrict__ row_ptr,
                                               const int* __restrict__ csr_src,
                                               const float* __restrict__ h2s,
                                               const float* __restrict__ dinv,
                                               const float* __restrict__ b2,
                                               float* __restrict__ out, int n) {
    int node = blockIdx.x * 4 + (threadIdx.x >> 6);
    if (node >= n) return;
    int lane = threadIdx.x & 63;
    int c = lane & 3, slot = lane >> 2;
    int start = row_ptr[node], end = row_ptr[node + 1];
    float acc = 0.f;
    for (int j = start + slot; j < end; j += 16)
        acc += h2s[(size_t)csr_src[j] * CDIM + c];
#pragma unroll
    for (int m = 4; m < 64; m <<= 1) acc += __shfl_xor(acc, m, 64);
    float z = dinv[node] * (acc + h2s[(size_t)node * CDIM + c]) + b2[c];
    float mx = fmaxf(z, __shfl_xor(z, 1, 64));
    mx = fmaxf(mx, __shfl_xor(mx, 2, 64));
    float ex = __expf(z - mx);
    float ssum = ex + __shfl_xor(ex, 1, 64);
    ssum += __shfl_xor(ssum, 2, 64);
    if (lane < 4) out[(size_t)node * CDIM + c] = z - mx - __logf(ssum);
}

extern "C" void kernel_launch(void* const* d_in, const int* in_sizes, int n_in,
                              void* d_out, int out_size, void* d_ws, size_t ws_size,
                              hipStream_t stream) {
    const float* x  = (const float*)d_in[0];
    const void*  ei = d_in[1];
    const float* W1 = (const float*)d_in[2];
    const float* b1 = (const float*)d_in[3];
    const float* W2 = (const float*)d_in[4];
    const float* b2 = (const float*)d_in[5];
    float* out = (float*)d_out;

    int n = in_sizes[0] / F_IN;   // 100000
    int E = in_sizes[1] / 2;      // 3200000

    char* ws = (char*)d_ws;
    size_t off = 0;
    auto alloc = [&](size_t bytes) {
        char* p = ws + off;
        off = (off + bytes + 255) & ~(size_t)255;
        return p;
    };
    int*   flag    = (int*)alloc(256);
    int*   deg_i   = (int*)alloc((size_t)n * 4);
    float* dinv    = (float*)alloc((size_t)n * 4);
    int*   row_ptr = (int*)alloc((size_t)(n + 1) * 4);
    int*   cursor  = (int*)alloc((size_t)n * 4);
    int*   part    = (int*)alloc(512 * 4);
    float* h1s     = (float*)alloc((size_t)n * HDIM * 4);
    float* h2s     = (float*)alloc((size_t)n * CDIM * 4);
    int*   csr_src = (int*)alloc((size_t)E * 4);
    (void)ws_size;

    int nb = (n + 1023) / 1024;  // 98 scan blocks

    hipLaunchKernelGGL(k_detect, dim3(1), dim3(256), 0, stream, (const int*)ei, flag);
    hipLaunchKernelGGL(k_zero_deg, dim3((n + 255) / 256), dim3(256), 0, stream,
                       deg_i, n);
    hipLaunchKernelGGL(k_hist, dim3((E + 255) / 256), dim3(256), 0, stream,
                       ei, flag, deg_i, E);
    hipLaunchKernelGGL(k_scan1, dim3(nb), dim3(256), 0, stream,
                       deg_i, row_ptr, part, n);
    hipLaunchKernelGGL(k_scan2, dim3(1), dim3(128), 0, stream, part, nb);
    hipLaunchKernelGGL(k_scan3, dim3((n + 255) / 256), dim3(256), 0, stream,
                       row_ptr, cursor, part, n, E);
    hipLaunchKernelGGL(k_rsqrt, dim3((n + 255) / 256), dim3(256), 0, stream,
                       deg_i, dinv, n);
    hipLaunchKernelGGL(k_gemm1, dim3((n + 15) / 16), dim3(256), 0, stream,
                       x, W1, dinv, h1s, n);
    hipLaunchKernelGGL(k_scatter, dim3((E + 255) / 256), dim3(256), 0, stream,
                       ei, flag, cursor, csr_src, E);
    hipLaunchKernelGGL(k_agg1f, dim3((n + 3) / 4), dim3(256), 0, stream,
                       row_ptr, csr_src, h1s, dinv, b1, W2, h2s, n);
    hipLaunchKernelGGL(k_agg2f, dim3((n + 3) / 4), dim3(256), 0, stream,
                       row_ptr, csr_src, h2s, dinv, b2, out, n);
}

// Round 10
// 604.920 us; speedup vs baseline: 2.6449x; 1.0183x over previous
//
#include <hip/hip_runtime.h>
#include <stdint.h>

#define F_IN 128
#define HDIM 16
#define CDIM 4
#define BSH  8          // 256 nodes per bucket
#define BNODES 256
#define SMASK 131071    // 17 bits for src (n < 131072)
#define TILE 8192       // bscatter tile: 512 thr x 16 edges

// int64 vs int32 edge_index detection (odd words all zero => int64).
__global__ void k_detect(const int* __restrict__ w, int* __restrict__ flag) {
    __shared__ int s_any;
    if (threadIdx.x == 0) s_any = 0;
    __syncthreads();
    int nz = 0;
    for (int k = threadIdx.x; k < 1024; k += blockDim.x) nz |= w[2 * k + 1];
    if (nz) atomicOr(&s_any, 1);
    __syncthreads();
    if (threadIdx.x == 0) *flag = (s_any == 0) ? 1 : 0;
}

__global__ void k_zero(int* __restrict__ bcnt) {
    bcnt[threadIdx.x] = 0;  // 512 threads, 512 counters
}

// Bucket histogram: LDS-private, one global atomic per bucket per block.
__global__ __launch_bounds__(256) void k_bhist(const void* __restrict__ ei,
                                               const int* __restrict__ flag,
                                               int* __restrict__ bcnt,
                                               int E, int nbuk) {
    __shared__ int h[512];
    for (int b = threadIdx.x; b < 512; b += 256) h[b] = 0;
    __syncthreads();
    int stride = gridDim.x * 256;
    bool f64 = (*flag != 0);
    for (int e = blockIdx.x * 256 + threadIdx.x; e < E; e += stride) {
        int d = f64 ? (int)((const long long*)ei)[E + e] : ((const int*)ei)[E + e];
        atomicAdd(&h[d >> BSH], 1);
    }
    __syncthreads();
    for (int b = threadIdx.x; b < nbuk; b += 256)
        if (h[b]) atomicAdd(&bcnt[b], h[b]);
}

// Exclusive scan of bucket counts -> base & cursor.
__global__ __launch_bounds__(512) void k_bscan(const int* __restrict__ bcnt,
                                               int* __restrict__ bbase,
                                               int* __restrict__ bcur,
                                               int nbuk, int E) {
    __shared__ int sd[512];
    int t = threadIdx.x;
    int own = (t < nbuk) ? bcnt[t] : 0;
    sd[t] = own;
    __syncthreads();
    for (int off = 1; off < 512; off <<= 1) {
        int x = (t >= off) ? sd[t - off] : 0;
        __syncthreads();
        sd[t] += x;
        __syncthreads();
    }
    if (t < nbuk) { int ex = sd[t] - own; bbase[t] = ex; bcur[t] = ex; }
    if (t == 0) bbase[nbuk] = E;
}

// Tile-phased multisplit: per tile, per-bucket contiguous runs (~84B) reserved
// with ONE global atomic per (tile,bucket). Payload: src | (dloc<<17), 4B.
__global__ __launch_bounds__(512) void k_bscatter(const void* __restrict__ ei,
                                                  const int* __restrict__ flag,
                                                  int* __restrict__ bcur,
                                                  int* __restrict__ bpk,
                                                  int E, int nbuk) {
    __shared__ int hist[512], loff[512], rbase[512];
    __shared__ int lpk[TILE];
    __shared__ unsigned short lb[TILE];
    int tid = threadIdx.x;
    int tstart = blockIdx.x * TILE;
    int cnt = min(TILE, E - tstart);
    for (int b = tid; b < 512; b += 512) { hist[b] = 0; loff[b] = 0; }
    __syncthreads();
    bool f64 = (*flag != 0);
    for (int k = 0; k < TILE / 512; ++k) {
        int i = tid + k * 512;
        if (i < cnt) {
            int e = tstart + i, s, d;
            if (f64) {
                const long long* q = (const long long*)ei;
                s = (int)q[e]; d = (int)q[E + e];
            } else {
                const int* q = (const int*)ei;
                s = q[e]; d = q[E + e];
            }
            int b = d >> BSH;
            lpk[i] = s | ((d & (BNODES - 1)) << 17);
            lb[i] = (unsigned short)b;
            atomicAdd(&hist[b], 1);
        }
    }
    __syncthreads();
    if (tid < nbuk && hist[tid] > 0) rbase[tid] = atomicAdd(&bcur[tid], hist[tid]);
    __syncthreads();
    for (int k = 0; k < TILE / 512; ++k) {
        int i = tid + k * 512;
        if (i < cnt) {
            int b = lb[i];
            int p = rbase[b] + atomicAdd(&loff[b], 1);
            bpk[p] = lpk[i];
        }
    }
}

// Per-bucket in-degree count -> dinv = rsqrt(deg+1). One block per bucket.
__global__ __launch_bounds__(256) void k_bdeg(const int* __restrict__ bbase,
                                              const int* __restrict__ bpk,
                                              float* __restrict__ dinv, int n) {
    __shared__ int cnt[BNODES];
    int b = blockIdx.x, tid = threadIdx.x;
    cnt[tid] = 0;
    __syncthreads();
    int start = bbase[b], end = bbase[b + 1];
    for (int i = start + tid; i < end; i += 256)
        atomicAdd(&cnt[bpk[i] >> 17], 1);
    __syncthreads();
    int g = b * BNODES + tid;
    if (g < n) dinv[g] = rsqrtf((float)(cnt[tid] + 1));
}

// h1s = (x @ W1) * dinv[row]  — LDS-tiled, 16 rows / 256-thread block.
__global__ __launch_bounds__(256) void k_gemm1(const float* __restrict__ x,
                                               const float* __restrict__ W1,
                                               const float* __restrict__ dinv,
                                               float* __restrict__ h1s, int n) {
    __shared__ float sW[F_IN * HDIM];
    __shared__ float sX[16][F_IN + 4];
    for (int i = threadIdx.x; i < F_IN * HDIM; i += 256) sW[i] = W1[i];
    int row0 = blockIdx.x * 16;
    const float4* x4 = (const float4*)(x + (size_t)row0 * F_IN);
    for (int i = threadIdx.x; i < 512; i += 256) {
        int r = i >> 5, c4 = i & 31;
        if (row0 + r < n) *(float4*)&sX[r][c4 * 4] = x4[i];
    }
    __syncthreads();
    int c = threadIdx.x & 15, r = threadIdx.x >> 4;
    float acc = 0.f;
#pragma unroll
    for (int k = 0; k < F_IN; ++k) acc += sX[r][k] * sW[k * HDIM + c];
    int row = row0 + r;
    if (row < n) h1s[(size_t)row * HDIM + c] = acc * dinv[row];
}

// Layer-1 bucket aggregation: LDS slab accumulate + fused bias/relu/W2.
// 16 lanes per edge; x2 unrolled gathers for latency hiding.
__global__ __launch_bounds__(512) void k_bagg1(const int* __restrict__ bbase,
                                               const int* __restrict__ bpk,
                                               const float* __restrict__ h1s,
                                               const float* __restrict__ dinv,
                                               const float* __restrict__ b1,
                                               const float* __restrict__ W2,
                                               float* __restrict__ h2s, int n) {
    __shared__ float slab[BNODES * HDIM];  // 16 KB
    int b = blockIdx.x, tid = threadIdx.x;
    for (int j = tid; j < BNODES * HDIM; j += 512) slab[j] = 0.f;
    __syncthreads();
    int start = bbase[b], end = bbase[b + 1];
    int f = tid & 15;
    int i = start + (tid >> 4);  // 32 edges in flight per block
    for (; i + 32 < end; i += 64) {
        int e0 = bpk[i], e1 = bpk[i + 32];
        float v0 = h1s[(size_t)(e0 & SMASK) * HDIM + f];
        float v1 = h1s[(size_t)(e1 & SMASK) * HDIM + f];
        atomicAdd(&slab[(e0 >> 17) * HDIM + f], v0);
        atomicAdd(&slab[(e1 >> 17) * HDIM + f], v1);
    }
    for (; i < end; i += 32) {
        int e0 = bpk[i];
        float v0 = h1s[(size_t)(e0 & SMASK) * HDIM + f];
        atomicAdd(&slab[(e0 >> 17) * HDIM + f], v0);
    }
    __syncthreads();
    if (tid < BNODES) {
        int g = b * BNODES + tid;
        if (g < n) {
            float di = dinv[g];
            float a0 = 0.f, a1 = 0.f, a2 = 0.f, a3 = 0.f;
#pragma unroll
            for (int j = 0; j < HDIM; ++j) {
                float t = fmaxf(di * (slab[tid * HDIM + j] +
                                      h1s[(size_t)g * HDIM + j]) + b1[j], 0.f);
                float4 w2 = ((const float4*)W2)[j];
                a0 += t * w2.x; a1 += t * w2.y; a2 += t * w2.z; a3 += t * w2.w;
            }
            ((float4*)h2s)[g] = make_float4(a0 * di, a1 * di, a2 * di, a3 * di);
        }
    }
}

// Layer-2 bucket aggregation: LDS slab + fused bias + log_softmax.
__global__ __launch_bounds__(512) void k_bagg2(const int* __restrict__ bbase,
                                               const int* __restrict__ bpk,
                                               const float* __restrict__ h2s,
                                               const float* __restrict__ dinv,
                                               const float* __restrict__ b2,
                                               float* __restrict__ out, int n) {
    __shared__ float slab[BNODES * CDIM];  // 4 KB
    int b = blockIdx.x, tid = threadIdx.x;
    for (int j = tid; j < BNODES * CDIM; j += 512) slab[j] = 0.f;
    __syncthreads();
    int start = bbase[b], end = bbase[b + 1];
    int c = tid & 3;
    int i = start + (tid >> 2);  // 128 edges in flight per block
    for (; i + 128 < end; i += 256) {
        int e0 = bpk[i], e1 = bpk[i + 128];
        float v0 = h2s[(size_t)(e0 & SMASK) * CDIM + c];
        float v1 = h2s[(size_t)(e1 & SMASK) * CDIM + c];
        atomicAdd(&slab[(e0 >> 17) * CDIM + c], v0);
        atomicAdd(&slab[(e1 >> 17) * CDIM + c], v1);
    }
    for (; i < end; i += 128) {
        int e0 = bpk[i];
        float v0 = h2s[(size_t)(e0 & SMASK) * CDIM + c];
        atomicAdd(&slab[(e0 >> 17) * CDIM + c], v0);
    }
    __syncthreads();
    if (tid < BNODES) {
        int g = b * BNODES + tid;
        if (g < n) {
            float di = dinv[g];
            float4 hs = ((const float4*)h2s)[g];
            float z0 = di * (slab[tid * 4 + 0] + hs.x) + b2[0];
            float z1 = di * (slab[tid * 4 + 1] + hs.y) + b2[1];
            float z2 = di * (slab[tid * 4 + 2] + hs.z) + b2[2];
            float z3 = di * (slab[tid * 4 + 3] + hs.w) + b2[3];
            float m = fmaxf(fmaxf(z0, z1), fmaxf(z2, z3));
            float s = expf(z0 - m) + expf(z1 - m) + expf(z2 - m) + expf(z3 - m);
            float l = m + logf(s);
            ((float4*)out)[g] = make_float4(z0 - l, z1 - l, z2 - l, z3 - l);
        }
    }
}

extern "C" void kernel_launch(void* const* d_in, const int* in_sizes, int n_in,
                              void* d_out, int out_size, void* d_ws, size_t ws_size,
                              hipStream_t stream) {
    const float* x  = (const float*)d_in[0];
    const void*  ei = d_in[1];
    const float* W1 = (const float*)d_in[2];
    const float* b1 = (const float*)d_in[3];
    const float* W2 = (const float*)d_in[4];
    const float* b2 = (const float*)d_in[5];
    float* out = (float*)d_out;

    int n = in_sizes[0] / F_IN;   // 100000
    int E = in_sizes[1] / 2;      // 3200000
    int nbuk = (n + BNODES - 1) >> BSH;  // 391

    char* ws = (char*)d_ws;
    size_t off = 0;
    auto alloc = [&](size_t bytes) {
        char* p = ws + off;
        off = (off + bytes + 255) & ~(size_t)255;
        return p;
    };
    int*   flag  = (int*)alloc(256);
    int*   bcnt  = (int*)alloc(512 * 4);
    int*   bbase = (int*)alloc(513 * 4);
    int*   bcur  = (int*)alloc(512 * 4);
    float* dinv  = (float*)alloc((size_t)n * 4);
    float* h1s   = (float*)alloc((size_t)n * HDIM * 4);
    float* h2s   = (float*)alloc((size_t)n * CDIM * 4);
    int*   bpk   = (int*)alloc((size_t)E * 4);
    (void)ws_size;

    int ntiles = (E + TILE - 1) / TILE;  // 391

    hipLaunchKernelGGL(k_detect, dim3(1), dim3(256), 0, stream, (const int*)ei, flag);
    hipLaunchKernelGGL(k_zero, dim3(1), dim3(512), 0, stream, bcnt);
    hipLaunchKernelGGL(k_bhist, dim3(256), dim3(256), 0, stream,
                       ei, flag, bcnt, E, nbuk);
    hipLaunchKernelGGL(k_bscan, dim3(1), dim3(512), 0, stream, bcnt, bbase, bcur,
                       nbuk, E);
    hipLaunchKernelGGL(k_bscatter, dim3(ntiles), dim3(512), 0, stream,
                       ei, flag, bcur, bpk, E, nbuk);
    hipLaunchKernelGGL(k_bdeg, dim3(nbuk), dim3(256), 0, stream, bbase, bpk, dinv, n);
    hipLaunchKernelGGL(k_gemm1, dim3((n + 15) / 16), dim3(256), 0, stream,
                       x, W1, dinv, h1s, n);
    hipLaunchKernelGGL(k_bagg1, dim3(nbuk), dim3(512), 0, stream,
                       bbase, bpk, h1s, dinv, b1, W2, h2s, n);
    hipLaunchKernelGGL(k_bagg2, dim3(nbuk), dim3(512), 0, stream,
                       bbase, bpk, h2s, dinv, b2, out, n);
}

// Round 16
// 599.652 us; speedup vs baseline: 2.6681x; 1.0088x over previous
//
#include <hip/hip_runtime.h>
#include <stdint.h>

#define F_IN 128
#define HDIM 16
#define CDIM 4
#define BSH  7          // 128 nodes per bucket
#define BNODES 128
#define SMASK 131071    // 17 bits for src (n < 131072)
#define TILE 8192       // bscatter tile: 512 thr x 16 edges
#define NBMAX 1024

// int64 vs int32 edge_index detection (odd words all zero => int64).
__global__ void k_detect(const int* __restrict__ w, int* __restrict__ flag) {
    __shared__ int s_any;
    if (threadIdx.x == 0) s_any = 0;
    __syncthreads();
    int nz = 0;
    for (int k = threadIdx.x; k < 1024; k += blockDim.x) nz |= w[2 * k + 1];
    if (nz) atomicOr(&s_any, 1);
    __syncthreads();
    if (threadIdx.x == 0) *flag = (s_any == 0) ? 1 : 0;
}

__global__ void k_zero(int* __restrict__ bcnt) {
    bcnt[threadIdx.x] = 0;  // 1024 threads, 1024 counters
}

// Bucket histogram: LDS-private, one global atomic per bucket per block.
__global__ __launch_bounds__(256) void k_bhist(const void* __restrict__ ei,
                                               const int* __restrict__ flag,
                                               int* __restrict__ bcnt,
                                               int E, int nbuk) {
    __shared__ int h[NBMAX];
    for (int b = threadIdx.x; b < NBMAX; b += 256) h[b] = 0;
    __syncthreads();
    int stride = gridDim.x * 256;
    bool f64 = (*flag != 0);
    for (int e = blockIdx.x * 256 + threadIdx.x; e < E; e += stride) {
        int d = f64 ? (int)((const long long*)ei)[E + e] : ((const int*)ei)[E + e];
        atomicAdd(&h[d >> BSH], 1);
    }
    __syncthreads();
    for (int b = threadIdx.x; b < nbuk; b += 256)
        if (h[b]) atomicAdd(&bcnt[b], h[b]);
}

// Exclusive scan of bucket counts -> base & cursor (single 1024-thread block).
__global__ __launch_bounds__(1024) void k_bscan(const int* __restrict__ bcnt,
                                                int* __restrict__ bbase,
                                                int* __restrict__ bcur,
                                                int nbuk, int E) {
    __shared__ int sd[1024];
    int t = threadIdx.x;
    int own = (t < nbuk) ? bcnt[t] : 0;
    sd[t] = own;
    __syncthreads();
    for (int off = 1; off < 1024; off <<= 1) {
        int x = (t >= off) ? sd[t - off] : 0;
        __syncthreads();
        sd[t] += x;
        __syncthreads();
    }
    if (t < nbuk) { int ex = sd[t] - own; bbase[t] = ex; bcur[t] = ex; }
    if (t == 0) bbase[nbuk] = E;
}

// Tile-phased multisplit: per tile, per-bucket contiguous runs reserved with
// ONE global atomic per (tile,bucket). Payload: src | (dloc<<17), 4B.
__global__ __launch_bounds__(512) void k_bscatter(const void* __restrict__ ei,
                                                  const int* __restrict__ flag,
                                                  int* __restrict__ bcur,
                                                  int* __restrict__ bpk,
                                                  int E, int nbuk) {
    __shared__ int hist[NBMAX], loff[NBMAX], rbase[NBMAX];
    __shared__ int lpk[TILE];
    __shared__ unsigned short lb[TILE];
    int tid = threadIdx.x;
    int tstart = blockIdx.x * TILE;
    int cnt = min(TILE, E - tstart);
    for (int b = tid; b < NBMAX; b += 512) { hist[b] = 0; loff[b] = 0; }
    __syncthreads();
    bool f64 = (*flag != 0);
    for (int k = 0; k < TILE / 512; ++k) {
        int i = tid + k * 512;
        if (i < cnt) {
            int e = tstart + i, s, d;
            if (f64) {
                const long long* q = (const long long*)ei;
                s = (int)q[e]; d = (int)q[E + e];
            } else {
                const int* q = (const int*)ei;
                s = q[e]; d = q[E + e];
            }
            int b = d >> BSH;
            lpk[i] = s | ((d & (BNODES - 1)) << 17);
            lb[i] = (unsigned short)b;
            atomicAdd(&hist[b], 1);
        }
    }
    __syncthreads();
    for (int b = tid; b < nbuk; b += 512)
        if (hist[b] > 0) rbase[b] = atomicAdd(&bcur[b], hist[b]);
    __syncthreads();
    for (int k = 0; k < TILE / 512; ++k) {
        int i = tid + k * 512;
        if (i < cnt) {
            int b = lb[i];
            int p = rbase[b] + atomicAdd(&loff[b], 1);
            bpk[p] = lpk[i];
        }
    }
}

// Per-bucket in-degree count -> dinv = rsqrt(deg+1). One block per bucket.
// 8-deep unrolled bpk reads.
__global__ __launch_bounds__(256) void k_bdeg(const int* __restrict__ bbase,
                                              const int* __restrict__ bpk,
                                              float* __restrict__ dinv, int n) {
    __shared__ int cnt[BNODES];
    int b = blockIdx.x, tid = threadIdx.x;
    if (tid < BNODES) cnt[tid] = 0;
    __syncthreads();
    int start = bbase[b], end = bbase[b + 1];
    for (int i = start + tid; i < end; i += 256 * 8) {
        int e[8];
#pragma unroll
        for (int u = 0; u < 8; ++u) {
            int idx = i + u * 256;
            e[u] = (idx < end) ? bpk[idx] : -1;
        }
#pragma unroll
        for (int u = 0; u < 8; ++u)
            if (e[u] >= 0) atomicAdd(&cnt[e[u] >> 17], 1);
    }
    __syncthreads();
    int g = b * BNODES + tid;
    if (tid < BNODES && g < n) dinv[g] = rsqrtf((float)(cnt[tid] + 1));
}

// h1s = (x @ W1) * dinv[row]  — LDS-tiled, 16 rows / 256-thread block.
__global__ __launch_bounds__(256) void k_gemm1(const float* __restrict__ x,
                                               const float* __restrict__ W1,
                                               const float* __restrict__ dinv,
                                               float* __restrict__ h1s, int n) {
    __shared__ float sW[F_IN * HDIM];
    __shared__ float sX[16][F_IN + 4];
    for (int i = threadIdx.x; i < F_IN * HDIM; i += 256) sW[i] = W1[i];
    int row0 = blockIdx.x * 16;
    const float4* x4 = (const float4*)(x + (size_t)row0 * F_IN);
    for (int i = threadIdx.x; i < 512; i += 256) {
        int r = i >> 5, c4 = i & 31;
        if (row0 + r < n) *(float4*)&sX[r][c4 * 4] = x4[i];
    }
    __syncthreads();
    int c = threadIdx.x & 15, r = threadIdx.x >> 4;
    float acc = 0.f;
#pragma unroll
    for (int k = 0; k < F_IN; ++k) acc += sX[r][k] * sW[k * HDIM + c];
    int row = row0 + r;
    if (row < n) h1s[(size_t)row * HDIM + c] = acc * dinv[row];
}

// Layer-1 bucket aggregation: LDS slab accumulate + fused bias/relu/W2.
// 16 lanes per edge; 8-deep software-pipelined gathers.
__global__ __launch_bounds__(512) void k_bagg1(const int* __restrict__ bbase,
                                               const int* __restrict__ bpk,
                                               const float* __restrict__ h1s,
                                               const float* __restrict__ dinv,
                                               const float* __restrict__ b1,
                                               const float* __restrict__ W2,
                                               float* __restrict__ h2s, int n) {
    __shared__ float slab[BNODES * HDIM];  // 8 KB
    int b = blockIdx.x, tid = threadIdx.x;
    for (int j = tid; j < BNODES * HDIM; j += 512) slab[j] = 0.f;
    __syncthreads();
    int start = bbase[b], end = bbase[b + 1];
    int f = tid & 15;
    for (int i = start + (tid >> 4); i < end; i += 32 * 8) {
        int e[8];
        float v[8];
#pragma unroll
        for (int u = 0; u < 8; ++u) {
            int idx = i + u * 32;
            e[u] = (idx < end) ? bpk[idx] : -1;
        }
#pragma unroll
        for (int u = 0; u < 8; ++u)
            v[u] = (e[u] >= 0) ? h1s[(size_t)(e[u] & SMASK) * HDIM + f] : 0.f;
#pragma unroll
        for (int u = 0; u < 8; ++u)
            if (e[u] >= 0) atomicAdd(&slab[(e[u] >> 17) * HDIM + f], v[u]);
    }
    __syncthreads();
    if (tid < BNODES) {
        int g = b * BNODES + tid;
        if (g < n) {
            float di = dinv[g];
            float a0 = 0.f, a1 = 0.f, a2 = 0.f, a3 = 0.f;
#pragma unroll
            for (int j = 0; j < HDIM; ++j) {
                float t = fmaxf(di * (slab[tid * HDIM + j] +
                                      h1s[(size_t)g * HDIM + j]) + b1[j], 0.f);
                float4 w2 = ((const float4*)W2)[j];
                a0 += t * w2.x; a1 += t * w2.y; a2 += t * w2.z; a3 += t * w2.w;
            }
            ((float4*)h2s)[g] = make_float4(a0 * di, a1 * di, a2 * di, a3 * di);
        }
    }
}

// Layer-2 bucket aggregation: LDS slab + fused bias + log_softmax.
// 4 lanes per edge; 8-deep software-pipelined gathers.
__global__ __launch_bounds__(512) void k_bagg2(const int* __restrict__ bbase,
                                               const int* __restrict__ bpk,
                                               const float* __restrict__ h2s,
                                               const float* __restrict__ dinv,
                                               const float* __restrict__ b2,
                                               float* __restrict__ out, int n) {
    __shared__ float slab[BNODES * CDIM];  // 2 KB
    int b = blockIdx.x, tid = threadIdx.x;
    for (int j = tid; j < BNODES * CDIM; j += 512) slab[j] = 0.f;
    __syncthreads();
    int start = bbase[b], end = bbase[b + 1];
    int c = tid & 3;
    for (int i = start + (tid >> 2); i < end; i += 128 * 8) {
        int e[8];
        float v[8];
#pragma unroll
        for (int u = 0; u < 8; ++u) {
            int idx = i + u * 128;
            e[u] = (idx < end) ? bpk[idx] : -1;
        }
#pragma unroll
        for (int u = 0; u < 8; ++u)
            v[u] = (e[u] >= 0) ? h2s[(size_t)(e[u] & SMASK) * CDIM + c] : 0.f;
#pragma unroll
        for (int u = 0; u < 8; ++u)
            if (e[u] >= 0) atomicAdd(&slab[(e[u] >> 17) * CDIM + c], v[u]);
    }
    __syncthreads();
    if (tid < BNODES) {
        int g = b * BNODES + tid;
        if (g < n) {
            float di = dinv[g];
            float4 hs = ((const float4*)h2s)[g];
            float z0 = di * (slab[tid * 4 + 0] + hs.x) + b2[0];
            float z1 = di * (slab[tid * 4 + 1] + hs.y) + b2[1];
            float z2 = di * (slab[tid * 4 + 2] + hs.z) + b2[2];
            float z3 = di * (slab[tid * 4 + 3] + hs.w) + b2[3];
            float m = fmaxf(fmaxf(z0, z1), fmaxf(z2, z3));
            float s = expf(z0 - m) + expf(z1 - m) + expf(z2 - m) + expf(z3 - m);
            float l = m + logf(s);
            ((float4*)out)[g] = make_float4(z0 - l, z1 - l, z2 - l, z3 - l);
        }
    }
}

extern "C" void kernel_launch(void* const* d_in, const int* in_sizes, int n_in,
                              void* d_out, int out_size, void* d_ws, size_t ws_size,
                              hipStream_t stream) {
    const float* x  = (const float*)d_in[0];
    const void*  ei = d_in[1];
    const float* W1 = (const float*)d_in[2];
    const float* b1 = (const float*)d_in[3];
    const float* W2 = (const float*)d_in[4];
    const float* b2 = (const float*)d_in[5];
    float* out = (float*)d_out;

    int n = in_sizes[0] / F_IN;   // 100000
    int E = in_sizes[1] / 2;      // 3200000
    int nbuk = (n + BNODES - 1) >> BSH;  // 782

    char* ws = (char*)d_ws;
    size_t off = 0;
    auto alloc = [&](size_t bytes) {
        char* p = ws + off;
        off = (off + bytes + 255) & ~(size_t)255;
        return p;
    };
    int*   flag  = (int*)alloc(256);
    int*   bcnt  = (int*)alloc(NBMAX * 4);
    int*   bbase = (int*)alloc((NBMAX + 1) * 4);
    int*   bcur  = (int*)alloc(NBMAX * 4);
    float* dinv  = (float*)alloc((size_t)n * 4);
    float* h1s   = (float*)alloc((size_t)n * HDIM * 4);
    float* h2s   = (float*)alloc((size_t)n * CDIM * 4);
    int*   bpk   = (int*)alloc((size_t)E * 4);
    (void)ws_size;

    int ntiles = (E + TILE - 1) / TILE;  // 391

    hipLaunchKernelGGL(k_detect, dim3(1), dim3(256), 0, stream, (const int*)ei, flag);
    hipLaunchKernelGGL(k_zero, dim3(1), dim3(NBMAX), 0, stream, bcnt);
    hipLaunchKernelGGL(k_bhist, dim3(256), dim3(256), 0, stream,
                       ei, flag, bcnt, E, nbuk);
    hipLaunchKernelGGL(k_bscan, dim3(1), dim3(1024), 0, stream, bcnt, bbase, bcur,
                       nbuk, E);
    hipLaunchKernelGGL(k_bscatter, dim3(ntiles), dim3(512), 0, stream,
                       ei, flag, bcur, bpk, E, nbuk);
    hipLaunchKernelGGL(k_bdeg, dim3(nbuk), dim3(256), 0, stream, bbase, bpk, dinv, n);
    hipLaunchKernelGGL(k_gemm1, dim3((n + 15) / 16), dim3(256), 0, stream,
                       x, W1, dinv, h1s, n);
    hipLaunchKernelGGL(k_bagg1, dim3(nbuk), dim3(512), 0, stream,
                       bbase, bpk, h1s, dinv, b1, W2, h2s, n);
    hipLaunchKernelGGL(k_bagg2, dim3(nbuk), dim3(512), 0, stream,
                       bbase, bpk, h2s, dinv, b2, out, n);
}